// Round 4
// baseline (603.622 us; speedup 1.0000x reference)
//
#include <hip/hip_runtime.h>
#include <stdint.h>

// Problem constants
#define BB 4
#define TT 2048
#define CC 1024
#define HH 16
#define DH 64
#define NQKV 3072

typedef __bf16 bf16_t;
typedef __attribute__((ext_vector_type(8))) __bf16 bf16x8;
typedef __attribute__((ext_vector_type(4))) float f32x4;

#define MFMA16(a, b, c) __builtin_amdgcn_mfma_f32_16x16x32_bf16((a), (b), (c), 0, 0, 0)

// load 8 contiguous elements as bf16x8 (fp32 source converts on the fly)
__device__ __forceinline__ bf16x8 ld8(const float* p) {
  const f32x4 u = *(const f32x4*)p;
  const f32x4 w = *(const f32x4*)(p + 4);
  bf16x8 r;
  r[0] = (bf16_t)u[0]; r[1] = (bf16_t)u[1]; r[2] = (bf16_t)u[2]; r[3] = (bf16_t)u[3];
  r[4] = (bf16_t)w[0]; r[5] = (bf16_t)w[1]; r[6] = (bf16_t)w[2]; r[7] = (bf16_t)w[3];
  return r;
}
__device__ __forceinline__ bf16x8 ld8(const bf16_t* p) { return *(const bf16x8*)p; }

// ---------------------------------------------------------------------------
// GEMM: C[m][n] = sum_k A[m][k] * W[n][k] (+ bias[n]); A:(M,1024) W:(N,1024) fp32
// EPI==0: qkv epilogue (RoPE on Q/K, scale folded into Q, scatter to B,H,T,dh; bf16)
// EPI==1: plain bias epilogue into fp32 out0 (M x 1024)
// ---------------------------------------------------------------------------
template <int EPI, typename TA>
__global__ __launch_bounds__(256) void gemm_k(
    const TA* __restrict__ A, const float* __restrict__ W,
    const float* __restrict__ bias,
    const float* __restrict__ fcos, const float* __restrict__ fsin,
    void* __restrict__ out0v, bf16_t* __restrict__ out1,
    bf16_t* __restrict__ out2) {
  __shared__ bf16_t Alds[128 * 32];
  __shared__ bf16_t Blds[128 * 32];
  const int K = 1024;
  const int tid = threadIdx.x;
  const int lane = tid & 63, wave = tid >> 6;
  const int quad = lane >> 4, c = lane & 15;
  const int wm = wave >> 1, wn = wave & 1;
  const int mbase = blockIdx.y * 128, nbase = blockIdx.x * 128;

  f32x4 acc[4][4];
#pragma unroll
  for (int i = 0; i < 4; ++i)
#pragma unroll
    for (int j = 0; j < 4; ++j) acc[i][j] = (f32x4){0.f, 0.f, 0.f, 0.f};

  // staging: 128x32 tile = 512 chunks of 8 elements; thread handles chunks tid, tid+256
  const int ch0 = tid, ch1 = tid + 256;
  const TA* ag0 = A + (mbase + (ch0 >> 2)) * K + (ch0 & 3) * 8;
  const TA* ag1 = A + (mbase + (ch1 >> 2)) * K + (ch1 & 3) * 8;
  const float* bg0 = W + (nbase + (ch0 >> 2)) * K + (ch0 & 3) * 8;
  const float* bg1 = W + (nbase + (ch1 >> 2)) * K + (ch1 & 3) * 8;

  for (int k0 = 0; k0 < K; k0 += 32) {
    // global loads issued before the barrier (latency overlap with prev compute)
    const bf16x8 a0 = ld8(ag0 + k0);
    const bf16x8 a1 = ld8(ag1 + k0);
    const bf16x8 b0 = ld8(bg0 + k0);
    const bf16x8 b1 = ld8(bg1 + k0);
    __syncthreads();  // previous tile's readers done
    *(bf16x8*)&Alds[ch0 * 8] = a0;
    *(bf16x8*)&Alds[ch1 * 8] = a1;
    *(bf16x8*)&Blds[ch0 * 8] = b0;
    *(bf16x8*)&Blds[ch1 * 8] = b1;
    __syncthreads();
    bf16x8 af[4], bfr[4];
#pragma unroll
    for (int mi = 0; mi < 4; ++mi)
      af[mi] = *(const bf16x8*)&Alds[(wm * 64 + mi * 16 + c) * 32 + quad * 8];
#pragma unroll
    for (int ni = 0; ni < 4; ++ni)
      bfr[ni] = *(const bf16x8*)&Blds[(wn * 64 + ni * 16 + c) * 32 + quad * 8];
#pragma unroll
    for (int mi = 0; mi < 4; ++mi)
#pragma unroll
      for (int ni = 0; ni < 4; ++ni)
        acc[mi][ni] = MFMA16(af[mi], bfr[ni], acc[mi][ni]);
  }

  // epilogue. C/D layout: col = lane&15 (+16*ni), row = quad*4 + r (+16*mi)
  const float qscale = 0.18033688011112042f;  // 0.125 * log2(e)
#pragma unroll
  for (int mi = 0; mi < 4; ++mi) {
#pragma unroll
    for (int ni = 0; ni < 4; ++ni) {
      const int n = nbase + wn * 64 + ni * 16 + c;
      const float bv = bias[n];
#pragma unroll
      for (int r = 0; r < 4; ++r) {
        const int m = mbase + wm * 64 + mi * 16 + quad * 4 + r;
        float v = acc[mi][ni][r] + bv;
        if (EPI == 0) {
          bf16_t* out0 = (bf16_t*)out0v;
          const int sel = n >> 10;        // 0=q 1=k 2=v
          const int nl = n & 1023;
          const int h = nl >> 6, d = nl & 63;
          const int b = m >> 11, t = m & 2047;
          const int dst = ((b * HH + h) * TT + t) * DH + d;
          if (sel < 2) {
            // RoPE: pair partner is in the adjacent lane (col n^1)
            const float pv = __shfl_xor(v, 1, 64);
            const int d2 = d >> 1;
            const float cs = fcos[t * 32 + d2];
            const float sn = fsin[t * 32 + d2];
            // even d: a*cos - b*sin ; odd d: a*sin + b*cos (a=even elem, b=odd elem)
            float o = ((d & 1) == 0) ? (v * cs - pv * sn) : (pv * sn + v * cs);
            if (sel == 0) {
              o *= qscale;
              out0[dst] = (bf16_t)o;
            } else {
              out1[dst] = (bf16_t)o;
            }
          } else {
            out2[dst] = (bf16_t)v;
          }
        } else {
          float* outf = (float*)out0v;
          outf[m * CC + n] = v;
        }
      }
    }
  }
}

// ---------------------------------------------------------------------------
// Flash attention, causal. Q pre-scaled by 0.125*log2(e) (exp2 domain).
// Grid: B*H*(T/64) blocks, 256 threads (4 waves; wave w owns q rows w*16..+15).
// ---------------------------------------------------------------------------
__global__ __launch_bounds__(256) void attn_k(const bf16_t* __restrict__ Q,
                                              const bf16_t* __restrict__ Kv,
                                              const bf16_t* __restrict__ V,
                                              bf16_t* __restrict__ O) {
  // stride-72 rows: 144B = 9*16B keeps ds_*_b128 aligned and breaks bank conflicts
  __shared__ bf16_t Klds[64 * 72];
  __shared__ bf16_t Vtlds[64 * 72];   // transposed: Vtlds[d][key]
  __shared__ bf16_t Plds[4 * 16 * 72];  // per-wave 16x64 P tile

  const int tid = threadIdx.x;
  const int lane = tid & 63, wave = tid >> 6;
  const int quad = lane >> 4, c = lane & 15;
  const int bi = blockIdx.x;
  const int qb = bi & 31, h = (bi >> 5) & 15, b = bi >> 9;
  const int qbase = qb * 64;

  const bf16_t* Qh = Q + ((b * HH + h) * TT) * DH;
  const bf16_t* Kh = Kv + ((b * HH + h) * TT) * DH;
  const bf16_t* Vh = V + ((b * HH + h) * TT) * DH;

  const f32x4 zero4 = {0.f, 0.f, 0.f, 0.f};

  // Q fragments (A-layout: m = lane&15, k = quad*8+j (+32))
  const int qrow = qbase + wave * 16 + c;
  const bf16x8 qf0 = *(const bf16x8*)(Qh + qrow * DH + quad * 8);
  const bf16x8 qf1 = *(const bf16x8*)(Qh + qrow * DH + 32 + quad * 8);

  f32x4 o_acc[4];
#pragma unroll
  for (int ni = 0; ni < 4; ++ni) o_acc[ni] = zero4;
  float m_r[4] = {-1e30f, -1e30f, -1e30f, -1e30f};
  float l_r[4] = {0.f, 0.f, 0.f, 0.f};

  for (int kb = 0; kb <= qb; ++kb) {
    const int kbase = kb * 64;
    __syncthreads();  // previous iteration's readers done
    // stage K (row-major, padded) and V (transposed, padded)
#pragma unroll
    for (int s = 0; s < 2; ++s) {
      const int ch = tid + s * 256;        // 512 chunks of 16B
      const int row = ch >> 3, col8 = ch & 7;
      const bf16x8 kvv = *(const bf16x8*)(Kh + (kbase + row) * DH + col8 * 8);
      *(bf16x8*)&Klds[row * 72 + col8 * 8] = kvv;
      const bf16x8 vv = *(const bf16x8*)(Vh + (kbase + row) * DH + col8 * 8);
#pragma unroll
      for (int j = 0; j < 8; ++j) Vtlds[(col8 * 8 + j) * 72 + row] = vv[j];
    }
    __syncthreads();

    // S = Q K^T  (C layout: col = key = ni*16 + c, row = q = quad*4 + r)
    f32x4 s[4];
#pragma unroll
    for (int ni = 0; ni < 4; ++ni) {
      const bf16x8 k0 = *(const bf16x8*)&Klds[(ni * 16 + c) * 72 + quad * 8];
      const bf16x8 k1 = *(const bf16x8*)&Klds[(ni * 16 + c) * 72 + 32 + quad * 8];
      f32x4 sni = MFMA16(qf0, k0, zero4);
      sni = MFMA16(qf1, k1, sni);
      s[ni] = sni;
    }

    if (kb == qb) {  // diagonal block: causal mask (key > q)
#pragma unroll
      for (int ni = 0; ni < 4; ++ni)
#pragma unroll
        for (int r = 0; r < 4; ++r) {
          const int key = kbase + ni * 16 + c;
          const int qg = qbase + wave * 16 + quad * 4 + r;
          if (key > qg) s[ni][r] = -1e30f;
        }
    }

    // online softmax (exp2 domain); row lives in the 16 lanes of one quad
    float mnew[4], alpha[4];
#pragma unroll
    for (int r = 0; r < 4; ++r) {
      float mx = fmaxf(fmaxf(s[0][r], s[1][r]), fmaxf(s[2][r], s[3][r]));
      mx = fmaxf(mx, __shfl_xor(mx, 1, 64));
      mx = fmaxf(mx, __shfl_xor(mx, 2, 64));
      mx = fmaxf(mx, __shfl_xor(mx, 4, 64));
      mx = fmaxf(mx, __shfl_xor(mx, 8, 64));
      mnew[r] = fmaxf(m_r[r], mx);
      alpha[r] = exp2f(m_r[r] - mnew[r]);
      m_r[r] = mnew[r];
    }

    float rowsum[4] = {0.f, 0.f, 0.f, 0.f};
#pragma unroll
    for (int ni = 0; ni < 4; ++ni)
#pragma unroll
      for (int r = 0; r < 4; ++r) {
        const float p = exp2f(s[ni][r] - mnew[r]);
        rowsum[r] += p;
        Plds[wave * 1152 + (quad * 4 + r) * 72 + ni * 16 + c] = (bf16_t)p;
      }
#pragma unroll
    for (int r = 0; r < 4; ++r) {
      float rs = rowsum[r];
      rs += __shfl_xor(rs, 1, 64);
      rs += __shfl_xor(rs, 2, 64);
      rs += __shfl_xor(rs, 4, 64);
      rs += __shfl_xor(rs, 8, 64);
      l_r[r] = l_r[r] * alpha[r] + rs;
    }
#pragma unroll
    for (int ni = 0; ni < 4; ++ni)
#pragma unroll
      for (int r = 0; r < 4; ++r) o_acc[ni][r] *= alpha[r];

    // block barrier: all waves' P LDS writes visible before fragment reads
    __syncthreads();

    // O += P V (A = P from LDS, B = V^T rows contiguous)
    const bf16x8 p0 = *(const bf16x8*)&Plds[wave * 1152 + c * 72 + quad * 8];
    const bf16x8 p1 = *(const bf16x8*)&Plds[wave * 1152 + c * 72 + 32 + quad * 8];
#pragma unroll
    for (int ni = 0; ni < 4; ++ni) {
      const bf16x8 v0 = *(const bf16x8*)&Vtlds[(ni * 16 + c) * 72 + quad * 8];
      const bf16x8 v1 = *(const bf16x8*)&Vtlds[(ni * 16 + c) * 72 + 32 + quad * 8];
      o_acc[ni] = MFMA16(p0, v0, o_acc[ni]);
      o_acc[ni] = MFMA16(p1, v1, o_acc[ni]);
    }
  }

  // epilogue: O[(b*T + q)][h*64 + d] = acc / l   (concat-head layout for proj)
#pragma unroll
  for (int r = 0; r < 4; ++r) {
    const int qg = qbase + wave * 16 + quad * 4 + r;
    const float inv = 1.0f / l_r[r];
#pragma unroll
    for (int ni = 0; ni < 4; ++ni) {
      O[(b * TT + qg) * CC + h * 64 + ni * 16 + c] = (bf16_t)(o_acc[ni][r] * inv);
    }
  }
}

// ---------------------------------------------------------------------------
extern "C" void kernel_launch(void* const* d_in, const int* in_sizes, int n_in,
                              void* d_out, int out_size, void* d_ws,
                              size_t ws_size, hipStream_t stream) {
  // Resolve inputs by unique element-count signature (robust to how the bool
  // mask is represented or whether it is passed at all).
  const float *x = nullptr, *fcos = nullptr, *fsin = nullptr;
  const float *qkv_w = nullptr, *qkv_b = nullptr, *proj_w = nullptr, *proj_b = nullptr;
  for (int i = 0; i < n_in; ++i) {
    const int s = in_sizes[i];
    const float* p = (const float*)d_in[i];
    if (s == BB * TT * CC) x = p;                       // 8388608
    else if (s == TT * (DH / 2)) { if (!fcos) fcos = p; else fsin = p; }  // 65536 x2
    else if (s == NQKV * CC) qkv_w = p;                 // 3145728
    else if (s == NQKV) qkv_b = p;                      // 3072
    else if (s == CC * CC) proj_w = p;                  // 1048576
    else if (s == CC) proj_b = p;                       // 1024
    // s == TT*TT (mask) -> unused; causality is structural
  }

  const size_t NE = (size_t)BB * TT * CC;  // 8388608 elements per buffer
  bf16_t* Qb = (bf16_t*)d_ws;
  bf16_t* Kb = Qb + NE;
  bf16_t* Vb = Kb + NE;
  bf16_t* Ob = Vb + NE;

  // 1) qkv = x @ qkv_w^T + b, fused RoPE + head-split (+0.125*log2e into Q)
  gemm_k<0, float><<<dim3(NQKV / 128, (BB * TT) / 128), 256, 0, stream>>>(
      x, qkv_w, qkv_b, fcos, fsin, (void*)Qb, Kb, Vb);
  // 2) causal flash attention -> Ob (B*T, C) bf16
  attn_k<<<dim3(BB * HH * (TT / 64)), 256, 0, stream>>>(Qb, Kb, Vb, Ob);
  // 3) out = Ob @ proj_w^T + proj_b (fp32 output)
  gemm_k<1, bf16_t><<<dim3(CC / 128, (BB * TT) / 128), 256, 0, stream>>>(
      Ob, proj_w, proj_b, nullptr, nullptr, d_out, nullptr, nullptr);
}

// Round 5
// 519.466 us; speedup vs baseline: 1.1620x; 1.1620x over previous
//
#include <hip/hip_runtime.h>
#include <stdint.h>

// Problem constants
#define BB 4
#define TT 2048
#define CC 1024
#define HH 16
#define DH 64
#define NQKV 3072

typedef __bf16 bf16_t;
typedef __attribute__((ext_vector_type(8))) __bf16 bf16x8;
typedef __attribute__((ext_vector_type(4))) float f32x4;

#define MFMA16(a, b, c) __builtin_amdgcn_mfma_f32_16x16x32_bf16((a), (b), (c), 0, 0, 0)

// load 8 contiguous elements as bf16x8 (fp32 source converts on the fly)
__device__ __forceinline__ bf16x8 ld8(const float* p) {
  const f32x4 u = *(const f32x4*)p;
  const f32x4 w = *(const f32x4*)(p + 4);
  bf16x8 r;
  r[0] = (bf16_t)u[0]; r[1] = (bf16_t)u[1]; r[2] = (bf16_t)u[2]; r[3] = (bf16_t)u[3];
  r[4] = (bf16_t)w[0]; r[5] = (bf16_t)w[1]; r[6] = (bf16_t)w[2]; r[7] = (bf16_t)w[3];
  return r;
}
__device__ __forceinline__ bf16x8 ld8(const bf16_t* p) { return *(const bf16x8*)p; }

// ---------------------------------------------------------------------------
// GEMM: C[m][n] = sum_k A[m][k] * W[n][k] (+ bias[n]); A:(M,1024) W:(N,1024) fp32
// EPI==0: qkv epilogue (RoPE on Q/K, scale folded into Q, scatter to B,H,T,dh; bf16)
// EPI==1: plain bias epilogue into fp32 out0 (M x 1024)
// ---------------------------------------------------------------------------
template <int EPI, typename TA>
__global__ __launch_bounds__(256) void gemm_k(
    const TA* __restrict__ A, const float* __restrict__ W,
    const float* __restrict__ bias,
    const float* __restrict__ fcos, const float* __restrict__ fsin,
    void* __restrict__ out0v, bf16_t* __restrict__ out1,
    bf16_t* __restrict__ out2) {
  __shared__ bf16_t Alds[128 * 32];
  __shared__ bf16_t Blds[128 * 32];
  const int K = 1024;
  const int tid = threadIdx.x;
  const int lane = tid & 63, wave = tid >> 6;
  const int quad = lane >> 4, c = lane & 15;
  const int wm = wave >> 1, wn = wave & 1;
  const int mbase = blockIdx.y * 128, nbase = blockIdx.x * 128;

  f32x4 acc[4][4];
#pragma unroll
  for (int i = 0; i < 4; ++i)
#pragma unroll
    for (int j = 0; j < 4; ++j) acc[i][j] = (f32x4){0.f, 0.f, 0.f, 0.f};

  // staging: 128x32 tile = 512 chunks of 8 elements; thread handles chunks tid, tid+256
  const int ch0 = tid, ch1 = tid + 256;
  const TA* ag0 = A + (mbase + (ch0 >> 2)) * K + (ch0 & 3) * 8;
  const TA* ag1 = A + (mbase + (ch1 >> 2)) * K + (ch1 & 3) * 8;
  const float* bg0 = W + (nbase + (ch0 >> 2)) * K + (ch0 & 3) * 8;
  const float* bg1 = W + (nbase + (ch1 >> 2)) * K + (ch1 & 3) * 8;

  for (int k0 = 0; k0 < K; k0 += 32) {
    // global loads issued before the barrier (latency overlap with prev compute)
    const bf16x8 a0 = ld8(ag0 + k0);
    const bf16x8 a1 = ld8(ag1 + k0);
    const bf16x8 b0 = ld8(bg0 + k0);
    const bf16x8 b1 = ld8(bg1 + k0);
    __syncthreads();  // previous tile's readers done
    *(bf16x8*)&Alds[ch0 * 8] = a0;
    *(bf16x8*)&Alds[ch1 * 8] = a1;
    *(bf16x8*)&Blds[ch0 * 8] = b0;
    *(bf16x8*)&Blds[ch1 * 8] = b1;
    __syncthreads();
    bf16x8 af[4], bfr[4];
#pragma unroll
    for (int mi = 0; mi < 4; ++mi)
      af[mi] = *(const bf16x8*)&Alds[(wm * 64 + mi * 16 + c) * 32 + quad * 8];
#pragma unroll
    for (int ni = 0; ni < 4; ++ni)
      bfr[ni] = *(const bf16x8*)&Blds[(wn * 64 + ni * 16 + c) * 32 + quad * 8];
#pragma unroll
    for (int mi = 0; mi < 4; ++mi)
#pragma unroll
      for (int ni = 0; ni < 4; ++ni)
        acc[mi][ni] = MFMA16(af[mi], bfr[ni], acc[mi][ni]);
  }

  // epilogue. C/D layout: col = lane&15 (+16*ni), row = quad*4 + r (+16*mi)
  const float qscale = 0.18033688011112042f;  // 0.125 * log2(e)
#pragma unroll
  for (int mi = 0; mi < 4; ++mi) {
#pragma unroll
    for (int ni = 0; ni < 4; ++ni) {
      const int n = nbase + wn * 64 + ni * 16 + c;
      const float bv = bias[n];
#pragma unroll
      for (int r = 0; r < 4; ++r) {
        const int m = mbase + wm * 64 + mi * 16 + quad * 4 + r;
        float v = acc[mi][ni][r] + bv;
        if (EPI == 0) {
          bf16_t* out0 = (bf16_t*)out0v;
          const int sel = n >> 10;        // 0=q 1=k 2=v
          const int nl = n & 1023;
          const int h = nl >> 6, d = nl & 63;
          const int b = m >> 11, t = m & 2047;
          const int dst = ((b * HH + h) * TT + t) * DH + d;
          if (sel < 2) {
            // RoPE: pair partner is in the adjacent lane (col n^1)
            const float pv = __shfl_xor(v, 1, 64);
            const int d2 = d >> 1;
            const float cs = fcos[t * 32 + d2];
            const float sn = fsin[t * 32 + d2];
            // even d: a*cos - b*sin ; odd d: a*sin + b*cos (a=even elem, b=odd elem)
            float o = ((d & 1) == 0) ? (v * cs - pv * sn) : (pv * sn + v * cs);
            if (sel == 0) {
              o *= qscale;
              out0[dst] = (bf16_t)o;
            } else {
              out1[dst] = (bf16_t)o;
            }
          } else {
            out2[dst] = (bf16_t)v;
          }
        } else {
          float* outf = (float*)out0v;
          outf[m * CC + n] = v;
        }
      }
    }
  }
}

// ---------------------------------------------------------------------------
// Flash attention, causal. Q pre-scaled by 0.125*log2(e) (exp2 domain).
// Grid: B*H*(T/64) blocks, 256 threads (4 waves; wave w owns q rows w*16..+15).
// LDS layout: XOR-swizzled 16B chunks — tile row r, logical chunk cc stored at
// chunk index r*8 + (cc ^ (r&7)). All b128 LDS ops conflict-free per 8-lane
// phase; kills the 4.0e7 SQ_LDS_BANK_CONFLICT of the stride-72 layout.
// ---------------------------------------------------------------------------
__global__ __launch_bounds__(256) void attn_k(const bf16_t* __restrict__ Q,
                                              const bf16_t* __restrict__ Kv,
                                              const bf16_t* __restrict__ V,
                                              bf16_t* __restrict__ O) {
  __shared__ bf16_t KS[64 * 64];        // K tile, swizzled row-major (8 KB)
  __shared__ bf16_t VtS[64 * 64];       // V^T tile: row=d, chunks=key (8 KB)
  __shared__ bf16_t PS[4 * 16 * 64];    // per-wave 16x64 P tile, swizzled (8 KB)

  const int tid = threadIdx.x;
  const int lane = tid & 63, wave = tid >> 6;
  const int quad = lane >> 4, c = lane & 15;
  const int bi = blockIdx.x;
  const int qb = bi & 31, h = (bi >> 5) & 15, b = bi >> 9;
  const int qbase = qb * 64;

  const bf16_t* Qh = Q + ((b * HH + h) * TT) * DH;
  const bf16_t* Kh = Kv + ((b * HH + h) * TT) * DH;
  const bf16_t* Vh = V + ((b * HH + h) * TT) * DH;

  const f32x4 zero4 = {0.f, 0.f, 0.f, 0.f};

  // Q fragments (A-layout: m = lane&15, k = quad*8+j (+32))
  const int qrow = qbase + wave * 16 + c;
  const bf16x8 qf0 = *(const bf16x8*)(Qh + qrow * DH + quad * 8);
  const bf16x8 qf1 = *(const bf16x8*)(Qh + qrow * DH + 32 + quad * 8);

  // staging indices
  const int kch0 = tid, kch1 = tid + 256;           // K: 512 chunks of 16B
  const int krow0 = kch0 >> 3, kc80 = kch0 & 7;
  const int krow1 = kch1 >> 3, kc81 = kch1 & 7;
  const int vsb = tid >> 2, vjp = tid & 3;          // V: 64 8x8 subblocks x 4 col-pairs
  const int vrg = vsb & 7, vc8 = vsb >> 3;          // rg varies fastest across lanes
  const int vd0 = vc8 * 8 + vjp * 2, vd1 = vd0 + 1;
  bf16_t* vdst0 = &VtS[(vd0 * 8 + (vrg ^ (vd0 & 7))) * 8];
  bf16_t* vdst1 = &VtS[(vd1 * 8 + (vrg ^ (vd1 & 7))) * 8];

  f32x4 o_acc[4];
#pragma unroll
  for (int ni = 0; ni < 4; ++ni) o_acc[ni] = zero4;
  float m_r[4] = {-1e30f, -1e30f, -1e30f, -1e30f};
  float l_r[4] = {0.f, 0.f, 0.f, 0.f};

  for (int kb = 0; kb <= qb; ++kb) {
    const int kbase = kb * 64;
    // issue global loads before the barrier (overlap with prev iter compute)
    const bf16x8 k0v = *(const bf16x8*)(Kh + (kbase + krow0) * DH + kc80 * 8);
    const bf16x8 k1v = *(const bf16x8*)(Kh + (kbase + krow1) * DH + kc81 * 8);
    uint32_t rv[8];
#pragma unroll
    for (int i = 0; i < 8; ++i)
      rv[i] = *(const uint32_t*)(Vh + (kbase + vrg * 8 + i) * DH + vd0);
    union { bf16x8 v; uint16_t u[8]; } colA, colB;
#pragma unroll
    for (int i = 0; i < 8; ++i) {
      colA.u[i] = (uint16_t)(rv[i] & 0xffffu);
      colB.u[i] = (uint16_t)(rv[i] >> 16);
    }
    __syncthreads();  // previous iteration's LDS readers done
    *(bf16x8*)&KS[(krow0 * 8 + (kc80 ^ (krow0 & 7))) * 8] = k0v;
    *(bf16x8*)&KS[(krow1 * 8 + (kc81 ^ (krow1 & 7))) * 8] = k1v;
    *(bf16x8*)vdst0 = colA.v;
    *(bf16x8*)vdst1 = colB.v;
    __syncthreads();

    // S = Q K^T  (C layout: col = key = ni*16 + c, row = q = quad*4 + r)
    f32x4 s[4];
#pragma unroll
    for (int ni = 0; ni < 4; ++ni) {
      const int key = ni * 16 + c;
      const bf16x8 kf0 = *(const bf16x8*)&KS[(key * 8 + (quad ^ (key & 7))) * 8];
      const bf16x8 kf1 = *(const bf16x8*)&KS[(key * 8 + ((quad + 4) ^ (key & 7))) * 8];
      f32x4 sni = MFMA16(qf0, kf0, zero4);
      sni = MFMA16(qf1, kf1, sni);
      s[ni] = sni;
    }

    if (kb == qb) {  // diagonal block: causal mask (key > q)
#pragma unroll
      for (int ni = 0; ni < 4; ++ni)
#pragma unroll
        for (int r = 0; r < 4; ++r) {
          const int key = kbase + ni * 16 + c;
          const int qg = qbase + wave * 16 + quad * 4 + r;
          if (key > qg) s[ni][r] = -1e30f;
        }
    }

    // online softmax (exp2 domain); row lives in the 16 lanes of one quad
    float mnew[4], alpha[4];
#pragma unroll
    for (int r = 0; r < 4; ++r) {
      float mx = fmaxf(fmaxf(s[0][r], s[1][r]), fmaxf(s[2][r], s[3][r]));
      mx = fmaxf(mx, __shfl_xor(mx, 1, 64));
      mx = fmaxf(mx, __shfl_xor(mx, 2, 64));
      mx = fmaxf(mx, __shfl_xor(mx, 4, 64));
      mx = fmaxf(mx, __shfl_xor(mx, 8, 64));
      mnew[r] = fmaxf(m_r[r], mx);
      alpha[r] = exp2f(m_r[r] - mnew[r]);
      m_r[r] = mnew[r];
    }

    float rowsum[4] = {0.f, 0.f, 0.f, 0.f};
#pragma unroll
    for (int ni = 0; ni < 4; ++ni)
#pragma unroll
      for (int r = 0; r < 4; ++r) {
        const float p = exp2f(s[ni][r] - mnew[r]);
        rowsum[r] += p;
        const int prow = quad * 4 + r, pcol = ni * 16 + c;
        PS[wave * 1024 + (prow * 8 + ((pcol >> 3) ^ (prow & 7))) * 8 + (pcol & 7)] =
            (bf16_t)p;
      }
#pragma unroll
    for (int r = 0; r < 4; ++r) {
      float rs = rowsum[r];
      rs += __shfl_xor(rs, 1, 64);
      rs += __shfl_xor(rs, 2, 64);
      rs += __shfl_xor(rs, 4, 64);
      rs += __shfl_xor(rs, 8, 64);
      l_r[r] = l_r[r] * alpha[r] + rs;
    }
#pragma unroll
    for (int ni = 0; ni < 4; ++ni)
#pragma unroll
      for (int r = 0; r < 4; ++r) o_acc[ni][r] *= alpha[r];

    // P region is per-wave: drain this wave's ds_writes before its ds_reads
    asm volatile("s_waitcnt lgkmcnt(0)" ::: "memory");

    // O += P V (A = P from LDS, B = V^T rows contiguous)
    const bf16x8 p0 = *(const bf16x8*)&PS[wave * 1024 + (c * 8 + (quad ^ (c & 7))) * 8];
    const bf16x8 p1 =
        *(const bf16x8*)&PS[wave * 1024 + (c * 8 + ((quad + 4) ^ (c & 7))) * 8];
#pragma unroll
    for (int ni = 0; ni < 4; ++ni) {
      const int dcol = ni * 16 + c;
      const bf16x8 v0 = *(const bf16x8*)&VtS[(dcol * 8 + (quad ^ (dcol & 7))) * 8];
      const bf16x8 v1 =
          *(const bf16x8*)&VtS[(dcol * 8 + ((quad + 4) ^ (dcol & 7))) * 8];
      o_acc[ni] = MFMA16(p0, v0, o_acc[ni]);
      o_acc[ni] = MFMA16(p1, v1, o_acc[ni]);
    }
  }

  // epilogue: O[(b*T + q)][h*64 + d] = acc / l   (concat-head layout for proj)
#pragma unroll
  for (int r = 0; r < 4; ++r) {
    const int qg = qbase + wave * 16 + quad * 4 + r;
    const float inv = 1.0f / l_r[r];
#pragma unroll
    for (int ni = 0; ni < 4; ++ni) {
      O[(b * TT + qg) * CC + h * 64 + ni * 16 + c] = (bf16_t)(o_acc[ni][r] * inv);
    }
  }
}

// ---------------------------------------------------------------------------
extern "C" void kernel_launch(void* const* d_in, const int* in_sizes, int n_in,
                              void* d_out, int out_size, void* d_ws,
                              size_t ws_size, hipStream_t stream) {
  // Resolve inputs by unique element-count signature (robust to how the bool
  // mask is represented or whether it is passed at all).
  const float *x = nullptr, *fcos = nullptr, *fsin = nullptr;
  const float *qkv_w = nullptr, *qkv_b = nullptr, *proj_w = nullptr, *proj_b = nullptr;
  for (int i = 0; i < n_in; ++i) {
    const int s = in_sizes[i];
    const float* p = (const float*)d_in[i];
    if (s == BB * TT * CC) x = p;                       // 8388608
    else if (s == TT * (DH / 2)) { if (!fcos) fcos = p; else fsin = p; }  // 65536 x2
    else if (s == NQKV * CC) qkv_w = p;                 // 3145728
    else if (s == NQKV) qkv_b = p;                      // 3072
    else if (s == CC * CC) proj_w = p;                  // 1048576
    else if (s == CC) proj_b = p;                       // 1024
    // s == TT*TT (mask) -> unused; causality is structural
  }

  const size_t NE = (size_t)BB * TT * CC;  // 8388608 elements per buffer
  bf16_t* Qb = (bf16_t*)d_ws;
  bf16_t* Kb = Qb + NE;
  bf16_t* Vb = Kb + NE;
  bf16_t* Ob = Vb + NE;

  // 1) qkv = x @ qkv_w^T + b, fused RoPE + head-split (+0.125*log2e into Q)
  gemm_k<0, float><<<dim3(NQKV / 128, (BB * TT) / 128), 256, 0, stream>>>(
      x, qkv_w, qkv_b, fcos, fsin, (void*)Qb, Kb, Vb);
  // 2) causal flash attention -> Ob (B*T, C) bf16
  attn_k<<<dim3(BB * HH * (TT / 64)), 256, 0, stream>>>(Qb, Kb, Vb, Ob);
  // 3) out = Ob @ proj_w^T + proj_b (fp32 output)
  gemm_k<1, bf16_t><<<dim3(CC / 128, (BB * TT) / 128), 256, 0, stream>>>(
      Ob, proj_w, proj_b, nullptr, nullptr, d_out, nullptr, nullptr);
}

// Round 6
// 460.031 us; speedup vs baseline: 1.3121x; 1.1292x over previous
//
#include <hip/hip_runtime.h>
#include <stdint.h>

// Problem constants
#define BB 4
#define TT 2048
#define CC 1024
#define HH 16
#define DH 64
#define NQKV 3072

typedef __bf16 bf16_t;
typedef __attribute__((ext_vector_type(8))) __bf16 bf16x8;
typedef __attribute__((ext_vector_type(4))) float f32x4;

#define MFMA16(a, b, c) __builtin_amdgcn_mfma_f32_16x16x32_bf16((a), (b), (c), 0, 0, 0)

// async global->LDS, 16B per lane. LDS dest = wave-uniform base + lane*16.
__device__ __forceinline__ void gll16(const void* g, void* l) {
  typedef const __attribute__((address_space(1))) void* gp_t;
  typedef __attribute__((address_space(3))) void* lp_t;
  __builtin_amdgcn_global_load_lds((gp_t)(uintptr_t)g, (lp_t)(uintptr_t)l, 16, 0, 0);
}

// ---------------------------------------------------------------------------
// fp32 -> bf16 convert, 8 elems/thread (n multiple of 2048)
// ---------------------------------------------------------------------------
__global__ __launch_bounds__(256) void cvt_k(const float* __restrict__ src,
                                             bf16_t* __restrict__ dst, int n) {
  const int i8 = (blockIdx.x * 256 + threadIdx.x) * 8;
  if (i8 < n) {
    const f32x4 a = *(const f32x4*)(src + i8);
    const f32x4 b = *(const f32x4*)(src + i8 + 4);
    bf16x8 r;
    r[0] = (bf16_t)a[0]; r[1] = (bf16_t)a[1]; r[2] = (bf16_t)a[2]; r[3] = (bf16_t)a[3];
    r[4] = (bf16_t)b[0]; r[5] = (bf16_t)b[1]; r[6] = (bf16_t)b[2]; r[7] = (bf16_t)b[3];
    *(bf16x8*)(dst + i8) = r;
  }
}

// ---------------------------------------------------------------------------
// GEMM (bf16 A, bf16 W): C[m][n] = sum_k A[m][k]*W[n][k] (+bias[n]); K=1024.
// m97 structure: global_load_lds width-16 staging, 128x128 tile, 16x16x32 MFMA.
// EPI==0: qkv epilogue (RoPE Q/K, 0.125*log2e folded into Q, scatter B,H,T,dh)
// EPI==1: bias epilogue into fp32 out0
// ---------------------------------------------------------------------------
template <int EPI>
__global__ __launch_bounds__(256) void gemm_k(
    const bf16_t* __restrict__ A, const bf16_t* __restrict__ W,
    const float* __restrict__ bias,
    const float* __restrict__ fcos, const float* __restrict__ fsin,
    void* __restrict__ out0v, bf16_t* __restrict__ out1,
    bf16_t* __restrict__ out2) {
  __shared__ bf16_t Alds[128 * 32];
  __shared__ bf16_t Blds[128 * 32];
  const int K = 1024;
  const int tid = threadIdx.x;
  const int lane = tid & 63, wave = tid >> 6;
  const int quad = lane >> 4, c = lane & 15;
  const int wm = wave >> 1, wn = wave & 1;
  const int mbase = blockIdx.y * 128, nbase = blockIdx.x * 128;

  f32x4 acc[4][4];
#pragma unroll
  for (int i = 0; i < 4; ++i)
#pragma unroll
    for (int j = 0; j < 4; ++j) acc[i][j] = (f32x4){0.f, 0.f, 0.f, 0.f};

  const int ch0 = tid, ch1 = tid + 256;  // 512 chunks of 16B per 128x32 tile
  const bf16_t* ag0 = A + (mbase + (ch0 >> 2)) * K + (ch0 & 3) * 8;
  const bf16_t* ag1 = A + (mbase + (ch1 >> 2)) * K + (ch1 & 3) * 8;
  const bf16_t* bg0 = W + (nbase + (ch0 >> 2)) * K + (ch0 & 3) * 8;
  const bf16_t* bg1 = W + (nbase + (ch1 >> 2)) * K + (ch1 & 3) * 8;

  for (int k0 = 0; k0 < K; k0 += 32) {
    __syncthreads();  // previous tile's readers done
    gll16(ag0 + k0, &Alds[ch0 * 8]);
    gll16(ag1 + k0, &Alds[ch1 * 8]);
    gll16(bg0 + k0, &Blds[ch0 * 8]);
    gll16(bg1 + k0, &Blds[ch1 * 8]);
    __syncthreads();  // DMA drained (compiler emits vmcnt(0) before barrier)
    bf16x8 af[4], bfr[4];
#pragma unroll
    for (int mi = 0; mi < 4; ++mi)
      af[mi] = *(const bf16x8*)&Alds[(wm * 64 + mi * 16 + c) * 32 + quad * 8];
#pragma unroll
    for (int ni = 0; ni < 4; ++ni)
      bfr[ni] = *(const bf16x8*)&Blds[(wn * 64 + ni * 16 + c) * 32 + quad * 8];
#pragma unroll
    for (int mi = 0; mi < 4; ++mi)
#pragma unroll
      for (int ni = 0; ni < 4; ++ni)
        acc[mi][ni] = MFMA16(af[mi], bfr[ni], acc[mi][ni]);
  }

  // epilogue. C/D layout: col = lane&15 (+16*ni), row = quad*4 + r (+16*mi)
  const float qscale = 0.18033688011112042f;  // 0.125 * log2(e)
#pragma unroll
  for (int mi = 0; mi < 4; ++mi) {
#pragma unroll
    for (int ni = 0; ni < 4; ++ni) {
      const int n = nbase + wn * 64 + ni * 16 + c;
      const float bv = bias[n];
#pragma unroll
      for (int r = 0; r < 4; ++r) {
        const int m = mbase + wm * 64 + mi * 16 + quad * 4 + r;
        float v = acc[mi][ni][r] + bv;
        if (EPI == 0) {
          bf16_t* out0 = (bf16_t*)out0v;
          const int sel = n >> 10;  // 0=q 1=k 2=v
          const int nl = n & 1023;
          const int h = nl >> 6, d = nl & 63;
          const int b = m >> 11, t = m & 2047;
          const int dst = ((b * HH + h) * TT + t) * DH + d;
          if (sel < 2) {
            const float pv = __shfl_xor(v, 1, 64);  // RoPE partner (col n^1)
            const int d2 = d >> 1;
            const float cs = fcos[t * 32 + d2];
            const float sn = fsin[t * 32 + d2];
            float o = ((d & 1) == 0) ? (v * cs - pv * sn) : (pv * sn + v * cs);
            if (sel == 0) {
              o *= qscale;
              out0[dst] = (bf16_t)o;
            } else {
              out1[dst] = (bf16_t)o;
            }
          } else {
            out2[dst] = (bf16_t)v;
          }
        } else {
          float* outf = (float*)out0v;
          outf[m * CC + n] = v;
        }
      }
    }
  }
}

// ---------------------------------------------------------------------------
// Flash attention, causal, BQ=128. Q pre-scaled by 0.125*log2(e) (exp2 domain).
// Grid: 1024 blocks = qt(16, longest-first) x h(16) x b(4); 256 thr, 4 waves;
// wave w owns q rows [qbase + w*32, +32) as two 16-row MFMA subtiles.
// K/V double-buffered in LDS (1 barrier/iter); next tile's global loads issued
// before compute. XOR-swizzled 16B-chunk LDS layout (R5-verified, 0 conflicts).
// ---------------------------------------------------------------------------
__global__ __launch_bounds__(256) void attn_k(const bf16_t* __restrict__ Q,
                                              const bf16_t* __restrict__ Kv,
                                              const bf16_t* __restrict__ V,
                                              bf16_t* __restrict__ O) {
  __shared__ bf16_t KS[2][64 * 64];   // 2 x 8 KB
  __shared__ bf16_t VtS[2][64 * 64];  // 2 x 8 KB, row=d, chunks=key
  __shared__ bf16_t PS[4][2][16 * 64];  // per-wave, per-subtile P (16 KB)

  const int tid = threadIdx.x;
  const int lane = tid & 63, wave = tid >> 6;
  const int quad = lane >> 4, c = lane & 15;
  const int bi = blockIdx.x;
  const int qt = 15 - (bi & 15), h = (bi >> 4) & 15, b = bi >> 8;
  const int qbase = qt * 128;

  const bf16_t* Qh = Q + ((b * HH + h) * TT) * DH;
  const bf16_t* Kh = Kv + ((b * HH + h) * TT) * DH;
  const bf16_t* Vh = V + ((b * HH + h) * TT) * DH;

  const f32x4 zero4 = {0.f, 0.f, 0.f, 0.f};

  // Q fragments: A-layout m = lane&15, k = quad*8+j (+32)
  bf16x8 qf[2][2];
#pragma unroll
  for (int sub = 0; sub < 2; ++sub) {
    const int row = qbase + wave * 32 + sub * 16 + c;
    qf[sub][0] = *(const bf16x8*)(Qh + row * DH + quad * 8);
    qf[sub][1] = *(const bf16x8*)(Qh + row * DH + 32 + quad * 8);
  }

  // staging indices
  const int krow0 = tid >> 3, kc8 = tid & 7;   // K chunks tid, tid+256
  const int krow1 = krow0 + 32;
  const int vsb = tid >> 2, vjp = tid & 3;     // V: 8x2 block per thread
  const int vrg = vsb & 7, vc8 = vsb >> 3;
  const int vd0 = vc8 * 8 + vjp * 2, vd1 = vd0 + 1;

  f32x4 o_acc[2][4];
#pragma unroll
  for (int sub = 0; sub < 2; ++sub)
#pragma unroll
    for (int ni = 0; ni < 4; ++ni) o_acc[sub][ni] = zero4;
  float m_r[2][4], l_r[2][4];
#pragma unroll
  for (int sub = 0; sub < 2; ++sub)
#pragma unroll
    for (int r = 0; r < 4; ++r) { m_r[sub][r] = -1e30f; l_r[sub][r] = 0.f; }

  const int nkv = 2 * qt + 2;

  // register-staged tile
  bf16x8 kr0, kr1;
  uint32_t vr[8];
  auto load_tile = [&](int kbase) {
    kr0 = *(const bf16x8*)(Kh + (kbase + krow0) * DH + kc8 * 8);
    kr1 = *(const bf16x8*)(Kh + (kbase + krow1) * DH + kc8 * 8);
#pragma unroll
    for (int i = 0; i < 8; ++i)
      vr[i] = *(const uint32_t*)(Vh + (kbase + vrg * 8 + i) * DH + vd0);
  };
  auto store_tile = [&](int buf) {
    *(bf16x8*)&KS[buf][(krow0 * 8 + (kc8 ^ (krow0 & 7))) * 8] = kr0;
    *(bf16x8*)&KS[buf][(krow1 * 8 + (kc8 ^ (krow1 & 7))) * 8] = kr1;
    union { bf16x8 v; uint16_t u[8]; } colA, colB;
#pragma unroll
    for (int i = 0; i < 8; ++i) {
      colA.u[i] = (uint16_t)(vr[i] & 0xffffu);
      colB.u[i] = (uint16_t)(vr[i] >> 16);
    }
    *(bf16x8*)&VtS[buf][(vd0 * 8 + (vrg ^ (vd0 & 7))) * 8] = colA.v;
    *(bf16x8*)&VtS[buf][(vd1 * 8 + (vrg ^ (vd1 & 7))) * 8] = colB.v;
  };

  load_tile(0);
  store_tile(0);
  __syncthreads();

  for (int kb = 0; kb < nkv; ++kb) {
    const int cur = kb & 1;
    const int kbase = kb * 64;
    const bool pre = (kb + 1 < nkv);
    if (pre) load_tile((kb + 1) * 64);  // in flight during compute below

    // K fragments (shared by both subtiles): 8 ds_read_b128
    bf16x8 kf[4][2];
#pragma unroll
    for (int ni = 0; ni < 4; ++ni) {
      const int key = ni * 16 + c;
      kf[ni][0] = *(const bf16x8*)&KS[cur][(key * 8 + (quad ^ (key & 7))) * 8];
      kf[ni][1] = *(const bf16x8*)&KS[cur][(key * 8 + ((quad + 4) ^ (key & 7))) * 8];
    }

    // S = Q K^T
    f32x4 s[2][4];
#pragma unroll
    for (int sub = 0; sub < 2; ++sub)
#pragma unroll
      for (int ni = 0; ni < 4; ++ni) {
        f32x4 t = MFMA16(qf[sub][0], kf[ni][0], zero4);
        t = MFMA16(qf[sub][1], kf[ni][1], t);
        s[sub][ni] = t;
      }

    // causal mask (only when this subtile intersects/precedes the kv block)
#pragma unroll
    for (int sub = 0; sub < 2; ++sub) {
      const int minq = qbase + wave * 32 + sub * 16;
      if (kbase + 63 > minq) {
#pragma unroll
        for (int ni = 0; ni < 4; ++ni)
#pragma unroll
          for (int r = 0; r < 4; ++r) {
            const int key = kbase + ni * 16 + c;
            const int qg = minq + quad * 4 + r;
            if (key > qg) s[sub][ni][r] = -1e30f;
          }
      }
    }

    // online softmax (exp2 domain), per subtile, row in 16 lanes of one quad
#pragma unroll
    for (int sub = 0; sub < 2; ++sub) {
      float mnew[4], alpha[4];
#pragma unroll
      for (int r = 0; r < 4; ++r) {
        float mx = fmaxf(fmaxf(s[sub][0][r], s[sub][1][r]),
                         fmaxf(s[sub][2][r], s[sub][3][r]));
        mx = fmaxf(mx, __shfl_xor(mx, 1, 64));
        mx = fmaxf(mx, __shfl_xor(mx, 2, 64));
        mx = fmaxf(mx, __shfl_xor(mx, 4, 64));
        mx = fmaxf(mx, __shfl_xor(mx, 8, 64));
        mnew[r] = fmaxf(m_r[sub][r], mx);
        alpha[r] = exp2f(m_r[sub][r] - mnew[r]);
        m_r[sub][r] = mnew[r];
      }
      float rowsum[4] = {0.f, 0.f, 0.f, 0.f};
#pragma unroll
      for (int ni = 0; ni < 4; ++ni)
#pragma unroll
        for (int r = 0; r < 4; ++r) {
          const float p = exp2f(s[sub][ni][r] - mnew[r]);
          rowsum[r] += p;
          const int prow = quad * 4 + r, pcol = ni * 16 + c;
          PS[wave][sub][(prow * 8 + ((pcol >> 3) ^ (prow & 7))) * 8 + (pcol & 7)] =
              (bf16_t)p;
        }
#pragma unroll
      for (int r = 0; r < 4; ++r) {
        float rs = rowsum[r];
        rs += __shfl_xor(rs, 1, 64);
        rs += __shfl_xor(rs, 2, 64);
        rs += __shfl_xor(rs, 4, 64);
        rs += __shfl_xor(rs, 8, 64);
        l_r[sub][r] = l_r[sub][r] * alpha[r] + rs;
#pragma unroll
        for (int ni = 0; ni < 4; ++ni) o_acc[sub][ni][r] *= alpha[r];
      }
    }

    // drain this wave's P ds_writes before its own ds_reads (PS is per-wave)
    asm volatile("s_waitcnt lgkmcnt(0)" ::: "memory");

    // V fragments (shared by both subtiles): 8 ds_read_b128
    bf16x8 vf[4][2];
#pragma unroll
    for (int ni = 0; ni < 4; ++ni) {
      const int dcol = ni * 16 + c;
      vf[ni][0] = *(const bf16x8*)&VtS[cur][(dcol * 8 + (quad ^ (dcol & 7))) * 8];
      vf[ni][1] =
          *(const bf16x8*)&VtS[cur][(dcol * 8 + ((quad + 4) ^ (dcol & 7))) * 8];
    }
#pragma unroll
    for (int sub = 0; sub < 2; ++sub) {
      const bf16x8 p0 =
          *(const bf16x8*)&PS[wave][sub][(c * 8 + (quad ^ (c & 7))) * 8];
      const bf16x8 p1 =
          *(const bf16x8*)&PS[wave][sub][(c * 8 + ((quad + 4) ^ (c & 7))) * 8];
#pragma unroll
      for (int ni = 0; ni < 4; ++ni) {
        o_acc[sub][ni] = MFMA16(p0, vf[ni][0], o_acc[sub][ni]);
        o_acc[sub][ni] = MFMA16(p1, vf[ni][1], o_acc[sub][ni]);
      }
    }

    if (pre) store_tile((kb + 1) & 1);  // other buffer; readers passed barrier kb-1
    __syncthreads();
  }

  // epilogue: O[(b*T + q)][h*64 + d] = acc / l (concat-head layout for proj)
#pragma unroll
  for (int sub = 0; sub < 2; ++sub)
#pragma unroll
    for (int r = 0; r < 4; ++r) {
      const int qg = qbase + wave * 32 + sub * 16 + quad * 4 + r;
      const float inv = 1.0f / l_r[sub][r];
#pragma unroll
      for (int ni = 0; ni < 4; ++ni)
        O[(b * TT + qg) * CC + h * 64 + ni * 16 + c] =
            (bf16_t)(o_acc[sub][ni][r] * inv);
    }
}

// ---------------------------------------------------------------------------
extern "C" void kernel_launch(void* const* d_in, const int* in_sizes, int n_in,
                              void* d_out, int out_size, void* d_ws,
                              size_t ws_size, hipStream_t stream) {
  // Resolve inputs by unique element-count signature.
  const float *x = nullptr, *fcos = nullptr, *fsin = nullptr;
  const float *qkv_w = nullptr, *qkv_b = nullptr, *proj_w = nullptr, *proj_b = nullptr;
  for (int i = 0; i < n_in; ++i) {
    const int s = in_sizes[i];
    const float* p = (const float*)d_in[i];
    if (s == BB * TT * CC) x = p;                        // 8388608
    else if (s == TT * (DH / 2)) { if (!fcos) fcos = p; else fsin = p; }
    else if (s == NQKV * CC) qkv_w = p;                  // 3145728
    else if (s == NQKV) qkv_b = p;                       // 3072
    else if (s == CC * CC) proj_w = p;                   // 1048576
    else if (s == CC) proj_b = p;                        // 1024
    // mask (TT*TT) unused; causality is structural
  }

  const size_t NE = (size_t)BB * TT * CC;  // 8388608
  bf16_t* Qb = (bf16_t*)d_ws;
  bf16_t* Kb = Qb + NE;
  bf16_t* Vb = Kb + NE;
  bf16_t* Ob = Vb + NE;
  // dead-region reuse (all hazard-free under stream ordering):
  bf16_t* xb = Ob;             // x_bf16 lives in Ob region until attn overwrites
  bf16_t* wqkvb = (bf16_t*)d_out;  // qkv_w bf16 in d_out until gemm3 writes it
  bf16_t* wpb = Qb;            // proj_w bf16 in Qb region (dead after attn)

  // converts
  cvt_k<<<dim3((int)(NE / 2048)), 256, 0, stream>>>(x, xb, (int)NE);
  cvt_k<<<dim3(NQKV * CC / 2048), 256, 0, stream>>>(qkv_w, wqkvb, NQKV * CC);

  // 1) qkv = x @ qkv_w^T + b, fused RoPE + head-split (+0.125*log2e into Q)
  gemm_k<0><<<dim3(NQKV / 128, (BB * TT) / 128), 256, 0, stream>>>(
      xb, wqkvb, qkv_b, fcos, fsin, (void*)Qb, Kb, Vb);
  // 2) causal flash attention -> Ob (B*T, C) bf16  (overwrites xb)
  attn_k<<<dim3(BB * HH * (TT / 128)), 256, 0, stream>>>(Qb, Kb, Vb, Ob);
  // 3) convert proj_w (Qb dead now), then out = Ob @ proj_w^T + proj_b (fp32)
  cvt_k<<<dim3(CC * CC / 2048), 256, 0, stream>>>(proj_w, wpb, CC * CC);
  gemm_k<1><<<dim3(CC / 128, (BB * TT) / 128), 256, 0, stream>>>(
      Ob, wpb, proj_b, nullptr, nullptr, d_out, nullptr, nullptr);
}

// Round 7
// 342.308 us; speedup vs baseline: 1.7634x; 1.3439x over previous
//
#include <hip/hip_runtime.h>
#include <stdint.h>

// Problem constants
#define BB 4
#define TT 2048
#define CC 1024
#define HH 16
#define DH 64
#define NQKV 3072

typedef __bf16 bf16_t;
typedef __attribute__((ext_vector_type(8))) __bf16 bf16x8;
typedef __attribute__((ext_vector_type(4))) float f32x4;

#define MFMA16(a, b, c) __builtin_amdgcn_mfma_f32_16x16x32_bf16((a), (b), (c), 0, 0, 0)

// async global->LDS, 16B per lane. LDS dest = wave-uniform base + lane*16.
__device__ __forceinline__ void gll16(const void* g, void* l) {
  typedef const __attribute__((address_space(1))) void* gp_t;
  typedef __attribute__((address_space(3))) void* lp_t;
  __builtin_amdgcn_global_load_lds((gp_t)(uintptr_t)g, (lp_t)(uintptr_t)l, 16, 0, 0);
}

// ---------------------------------------------------------------------------
// fp32 -> bf16 convert, 8 elems/thread (n multiple of 2048)
// ---------------------------------------------------------------------------
__global__ __launch_bounds__(256) void cvt_k(const float* __restrict__ src,
                                             bf16_t* __restrict__ dst, int n) {
  const int i8 = (blockIdx.x * 256 + threadIdx.x) * 8;
  if (i8 < n) {
    const f32x4 a = *(const f32x4*)(src + i8);
    const f32x4 b = *(const f32x4*)(src + i8 + 4);
    bf16x8 r;
    r[0] = (bf16_t)a[0]; r[1] = (bf16_t)a[1]; r[2] = (bf16_t)a[2]; r[3] = (bf16_t)a[3];
    r[4] = (bf16_t)b[0]; r[5] = (bf16_t)b[1]; r[6] = (bf16_t)b[2]; r[7] = (bf16_t)b[3];
    *(bf16x8*)(dst + i8) = r;
  }
}

// ---------------------------------------------------------------------------
// GEMM (bf16 A, bf16 W): C[m][n] = sum_k A[m][k]*W[n][k] (+bias[n]); K=1024.
// m97 structure: global_load_lds width-16 staging, 128x128 tile, 16x16x32 MFMA.
// EPI==0: qkv epilogue (RoPE Q/K, 0.125*log2e folded into Q, scatter B,H,T,dh)
// EPI==1: bias epilogue into fp32 out0
// ---------------------------------------------------------------------------
template <int EPI>
__global__ __launch_bounds__(256) void gemm_k(
    const bf16_t* __restrict__ A, const bf16_t* __restrict__ W,
    const float* __restrict__ bias,
    const float* __restrict__ fcos, const float* __restrict__ fsin,
    void* __restrict__ out0v, bf16_t* __restrict__ out1,
    bf16_t* __restrict__ out2) {
  __shared__ bf16_t Alds[128 * 32];
  __shared__ bf16_t Blds[128 * 32];
  const int K = 1024;
  const int tid = threadIdx.x;
  const int lane = tid & 63, wave = tid >> 6;
  const int quad = lane >> 4, c = lane & 15;
  const int wm = wave >> 1, wn = wave & 1;
  const int mbase = blockIdx.y * 128, nbase = blockIdx.x * 128;

  f32x4 acc[4][4];
#pragma unroll
  for (int i = 0; i < 4; ++i)
#pragma unroll
    for (int j = 0; j < 4; ++j) acc[i][j] = (f32x4){0.f, 0.f, 0.f, 0.f};

  const int ch0 = tid, ch1 = tid + 256;  // 512 chunks of 16B per 128x32 tile
  const bf16_t* ag0 = A + (mbase + (ch0 >> 2)) * K + (ch0 & 3) * 8;
  const bf16_t* ag1 = A + (mbase + (ch1 >> 2)) * K + (ch1 & 3) * 8;
  const bf16_t* bg0 = W + (nbase + (ch0 >> 2)) * K + (ch0 & 3) * 8;
  const bf16_t* bg1 = W + (nbase + (ch1 >> 2)) * K + (ch1 & 3) * 8;

  for (int k0 = 0; k0 < K; k0 += 32) {
    __syncthreads();  // previous tile's readers done
    gll16(ag0 + k0, &Alds[ch0 * 8]);
    gll16(ag1 + k0, &Alds[ch1 * 8]);
    gll16(bg0 + k0, &Blds[ch0 * 8]);
    gll16(bg1 + k0, &Blds[ch1 * 8]);
    __syncthreads();  // DMA drained (compiler emits vmcnt(0) before barrier)
    bf16x8 af[4], bfr[4];
#pragma unroll
    for (int mi = 0; mi < 4; ++mi)
      af[mi] = *(const bf16x8*)&Alds[(wm * 64 + mi * 16 + c) * 32 + quad * 8];
#pragma unroll
    for (int ni = 0; ni < 4; ++ni)
      bfr[ni] = *(const bf16x8*)&Blds[(wn * 64 + ni * 16 + c) * 32 + quad * 8];
#pragma unroll
    for (int mi = 0; mi < 4; ++mi)
#pragma unroll
      for (int ni = 0; ni < 4; ++ni)
        acc[mi][ni] = MFMA16(af[mi], bfr[ni], acc[mi][ni]);
  }

  // epilogue. C/D layout: col = lane&15 (+16*ni), row = quad*4 + r (+16*mi)
  const float qscale = 0.18033688011112042f;  // 0.125 * log2(e)
#pragma unroll
  for (int mi = 0; mi < 4; ++mi) {
#pragma unroll
    for (int ni = 0; ni < 4; ++ni) {
      const int n = nbase + wn * 64 + ni * 16 + c;
      const float bv = bias[n];
#pragma unroll
      for (int r = 0; r < 4; ++r) {
        const int m = mbase + wm * 64 + mi * 16 + quad * 4 + r;
        float v = acc[mi][ni][r] + bv;
        if (EPI == 0) {
          bf16_t* out0 = (bf16_t*)out0v;
          const int sel = n >> 10;  // 0=q 1=k 2=v
          const int nl = n & 1023;
          const int h = nl >> 6, d = nl & 63;
          const int b = m >> 11, t = m & 2047;
          const int dst = ((b * HH + h) * TT + t) * DH + d;
          if (sel < 2) {
            const float pv = __shfl_xor(v, 1, 64);  // RoPE partner (col n^1)
            const int d2 = d >> 1;
            const float cs = fcos[t * 32 + d2];
            const float sn = fsin[t * 32 + d2];
            float o = ((d & 1) == 0) ? (v * cs - pv * sn) : (pv * sn + v * cs);
            if (sel == 0) {
              o *= qscale;
              out0[dst] = (bf16_t)o;
            } else {
              out1[dst] = (bf16_t)o;
            }
          } else {
            out2[dst] = (bf16_t)v;
          }
        } else {
          float* outf = (float*)out0v;
          outf[m * CC + n] = v;
        }
      }
    }
  }
}

// ---------------------------------------------------------------------------
// Flash attention, causal. Q pre-scaled by 0.125*log2(e) (exp2 domain).
// Uniform-work causal pairing: block bi handles q-tiles qtA=pair and
// qtB=31-pair (64 rows each) sequentially -> every block does exactly 33
// kv-iterations regardless of scheduling. Grid 1024 = pair(16) x h(16) x b(4),
// 256 thr / 4 waves; wave w owns 16 q-rows of the current tile.
// K/V double-buffered (1 barrier/iter), prefetch crosses the phase boundary.
// XOR-swizzled 16B-chunk LDS layout (R5-verified, 0 bank conflicts).
// ---------------------------------------------------------------------------
__global__ __launch_bounds__(256, 4) void attn_k(const bf16_t* __restrict__ Q,
                                                 const bf16_t* __restrict__ Kv,
                                                 const bf16_t* __restrict__ V,
                                                 bf16_t* __restrict__ O) {
  __shared__ bf16_t KS[2][64 * 64];    // 16 KB
  __shared__ bf16_t VtS[2][64 * 64];   // 16 KB, row=d, chunks=key
  __shared__ bf16_t PS[4][16 * 64];    // per-wave P tile, 8 KB

  const int tid = threadIdx.x;
  const int lane = tid & 63, wave = tid >> 6;
  const int quad = lane >> 4, c = lane & 15;
  const int bi = blockIdx.x;
  const int pair = bi & 15, h = (bi >> 4) & 15, b = bi >> 8;
  const int qtA = pair, qtB = 31 - pair;  // 64-row q-tile indices
  const int nA = qtA + 1;                 // kv tiles in phase A
  const int nflat = 33;                   // uniform total kv tiles per block

  const bf16_t* Qh = Q + ((b * HH + h) * TT) * DH;
  const bf16_t* Kh = Kv + ((b * HH + h) * TT) * DH;
  const bf16_t* Vh = V + ((b * HH + h) * TT) * DH;

  const f32x4 zero4 = {0.f, 0.f, 0.f, 0.f};

  // staging indices (R5-verified swizzle)
  const int krow0 = tid >> 3, kc8 = tid & 7;
  const int krow1 = krow0 + 32;
  const int vsb = tid >> 2, vjp = tid & 3;
  const int vrg = vsb & 7, vc8 = vsb >> 3;
  const int vd0 = vc8 * 8 + vjp * 2, vd1 = vd0 + 1;

  bf16x8 kr0, kr1;
  uint32_t vr[8];
  auto load_tile = [&](int kbase) {
    kr0 = *(const bf16x8*)(Kh + (kbase + krow0) * DH + kc8 * 8);
    kr1 = *(const bf16x8*)(Kh + (kbase + krow1) * DH + kc8 * 8);
#pragma unroll
    for (int i = 0; i < 8; ++i)
      vr[i] = *(const uint32_t*)(Vh + (kbase + vrg * 8 + i) * DH + vd0);
  };
  auto store_tile = [&](int buf) {
    *(bf16x8*)&KS[buf][(krow0 * 8 + (kc8 ^ (krow0 & 7))) * 8] = kr0;
    *(bf16x8*)&KS[buf][(krow1 * 8 + (kc8 ^ (krow1 & 7))) * 8] = kr1;
    union { bf16x8 v; uint16_t u[8]; } colA, colB;
#pragma unroll
    for (int i = 0; i < 8; ++i) {
      colA.u[i] = (uint16_t)(vr[i] & 0xffffu);
      colB.u[i] = (uint16_t)(vr[i] >> 16);
    }
    *(bf16x8*)&VtS[buf][(vd0 * 8 + (vrg ^ (vd0 & 7))) * 8] = colA.v;
    *(bf16x8*)&VtS[buf][(vd1 * 8 + (vrg ^ (vd1 & 7))) * 8] = colB.v;
  };
  auto kb_of = [&](int fi) { return fi < nA ? fi : fi - nA; };

  // phase state (A first)
  int qtbase = qtA * 64;
  int qrow = qtbase + wave * 16 + c;
  bf16x8 qf0 = *(const bf16x8*)(Qh + qrow * DH + quad * 8);
  bf16x8 qf1 = *(const bf16x8*)(Qh + qrow * DH + 32 + quad * 8);

  f32x4 o_acc[4] = {zero4, zero4, zero4, zero4};
  float m_r[4] = {-1e30f, -1e30f, -1e30f, -1e30f};
  float l_r[4] = {0.f, 0.f, 0.f, 0.f};

  auto write_O = [&](int qtb) {
#pragma unroll
    for (int r = 0; r < 4; ++r) {
      const int qg = qtb + wave * 16 + quad * 4 + r;
      const float inv = 1.0f / l_r[r];
#pragma unroll
      for (int ni = 0; ni < 4; ++ni)
        O[(b * TT + qg) * CC + h * 64 + ni * 16 + c] =
            (bf16_t)(o_acc[ni][r] * inv);
    }
  };

  load_tile(0);
  store_tile(0);
  __syncthreads();

  for (int fi = 0; fi < nflat; ++fi) {
    const int cur = fi & 1;
    const int kbase = kb_of(fi) * 64;
    const bool pre = (fi + 1 < nflat);
    if (pre) load_tile(kb_of(fi + 1) * 64);  // in flight during compute

    // K fragments: 8 ds_read_b128
    bf16x8 kf[4][2];
#pragma unroll
    for (int ni = 0; ni < 4; ++ni) {
      const int key = ni * 16 + c;
      kf[ni][0] = *(const bf16x8*)&KS[cur][(key * 8 + (quad ^ (key & 7))) * 8];
      kf[ni][1] = *(const bf16x8*)&KS[cur][(key * 8 + ((quad + 4) ^ (key & 7))) * 8];
    }

    // S = Q K^T (C layout: col = key = ni*16+c, row = quad*4+r)
    f32x4 s[4];
#pragma unroll
    for (int ni = 0; ni < 4; ++ni) {
      f32x4 t = MFMA16(qf0, kf[ni][0], zero4);
      t = MFMA16(qf1, kf[ni][1], t);
      s[ni] = t;
    }

    // causal mask (diag tile only, by construction of the schedule)
    const int minq = qtbase + wave * 16;
    if (kbase + 63 > minq) {
#pragma unroll
      for (int ni = 0; ni < 4; ++ni)
#pragma unroll
        for (int r = 0; r < 4; ++r) {
          const int key = kbase + ni * 16 + c;
          const int qg = minq + quad * 4 + r;
          if (key > qg) s[ni][r] = -1e30f;
        }
    }

    // online softmax (exp2 domain); row lives in 16 lanes of one quad
    float mnew[4], alpha[4];
#pragma unroll
    for (int r = 0; r < 4; ++r) {
      float mx = fmaxf(fmaxf(s[0][r], s[1][r]), fmaxf(s[2][r], s[3][r]));
      mx = fmaxf(mx, __shfl_xor(mx, 1, 64));
      mx = fmaxf(mx, __shfl_xor(mx, 2, 64));
      mx = fmaxf(mx, __shfl_xor(mx, 4, 64));
      mx = fmaxf(mx, __shfl_xor(mx, 8, 64));
      mnew[r] = fmaxf(m_r[r], mx);
      alpha[r] = exp2f(m_r[r] - mnew[r]);
      m_r[r] = mnew[r];
    }
    float rowsum[4] = {0.f, 0.f, 0.f, 0.f};
#pragma unroll
    for (int ni = 0; ni < 4; ++ni)
#pragma unroll
      for (int r = 0; r < 4; ++r) {
        const float p = exp2f(s[ni][r] - mnew[r]);
        rowsum[r] += p;
        const int prow = quad * 4 + r, pcol = ni * 16 + c;
        PS[wave][(prow * 8 + ((pcol >> 3) ^ (prow & 7))) * 8 + (pcol & 7)] =
            (bf16_t)p;
      }
#pragma unroll
    for (int r = 0; r < 4; ++r) {
      float rs = rowsum[r];
      rs += __shfl_xor(rs, 1, 64);
      rs += __shfl_xor(rs, 2, 64);
      rs += __shfl_xor(rs, 4, 64);
      rs += __shfl_xor(rs, 8, 64);
      l_r[r] = l_r[r] * alpha[r] + rs;
#pragma unroll
      for (int ni = 0; ni < 4; ++ni) o_acc[ni][r] *= alpha[r];
    }

    // PS is per-wave: drain this wave's ds_writes before its own ds_reads
    asm volatile("s_waitcnt lgkmcnt(0)" ::: "memory");

    const bf16x8 p0 = *(const bf16x8*)&PS[wave][(c * 8 + (quad ^ (c & 7))) * 8];
    const bf16x8 p1 =
        *(const bf16x8*)&PS[wave][(c * 8 + ((quad + 4) ^ (c & 7))) * 8];
#pragma unroll
    for (int ni = 0; ni < 4; ++ni) {
      const int dcol = ni * 16 + c;
      const bf16x8 v0 = *(const bf16x8*)&VtS[cur][(dcol * 8 + (quad ^ (dcol & 7))) * 8];
      const bf16x8 v1 =
          *(const bf16x8*)&VtS[cur][(dcol * 8 + ((quad + 4) ^ (dcol & 7))) * 8];
      o_acc[ni] = MFMA16(p0, v0, o_acc[ni]);
      o_acc[ni] = MFMA16(p1, v1, o_acc[ni]);
    }

    // phase A -> B transition (after A's diagonal tile)
    if (fi == nA - 1) {
      write_O(qtbase);
      qtbase = qtB * 64;
      qrow = qtbase + wave * 16 + c;
      qf0 = *(const bf16x8*)(Qh + qrow * DH + quad * 8);
      qf1 = *(const bf16x8*)(Qh + qrow * DH + 32 + quad * 8);
#pragma unroll
      for (int r = 0; r < 4; ++r) { m_r[r] = -1e30f; l_r[r] = 0.f; }
#pragma unroll
      for (int ni = 0; ni < 4; ++ni) o_acc[ni] = zero4;
    }

    if (pre) store_tile((fi + 1) & 1);
    __syncthreads();
  }

  write_O(qtbase);  // phase B epilogue
}

// ---------------------------------------------------------------------------
extern "C" void kernel_launch(void* const* d_in, const int* in_sizes, int n_in,
                              void* d_out, int out_size, void* d_ws,
                              size_t ws_size, hipStream_t stream) {
  // Resolve inputs by unique element-count signature.
  const float *x = nullptr, *fcos = nullptr, *fsin = nullptr;
  const float *qkv_w = nullptr, *qkv_b = nullptr, *proj_w = nullptr, *proj_b = nullptr;
  for (int i = 0; i < n_in; ++i) {
    const int s = in_sizes[i];
    const float* p = (const float*)d_in[i];
    if (s == BB * TT * CC) x = p;                        // 8388608
    else if (s == TT * (DH / 2)) { if (!fcos) fcos = p; else fsin = p; }
    else if (s == NQKV * CC) qkv_w = p;                  // 3145728
    else if (s == NQKV) qkv_b = p;                       // 3072
    else if (s == CC * CC) proj_w = p;                   // 1048576
    else if (s == CC) proj_b = p;                        // 1024
    // mask (TT*TT) unused; causality is structural
  }

  const size_t NE = (size_t)BB * TT * CC;  // 8388608
  bf16_t* Qb = (bf16_t*)d_ws;
  bf16_t* Kb = Qb + NE;
  bf16_t* Vb = Kb + NE;
  bf16_t* Ob = Vb + NE;
  // dead-region reuse (all hazard-free under stream ordering):
  bf16_t* xb = Ob;                 // x_bf16 lives in Ob region until attn
  bf16_t* wqkvb = (bf16_t*)d_out;  // qkv_w bf16 in d_out until gemm3 writes it
  bf16_t* wpb = Qb;                // proj_w bf16 in Qb region (dead after attn)

  // converts
  cvt_k<<<dim3((int)(NE / 2048)), 256, 0, stream>>>(x, xb, (int)NE);
  cvt_k<<<dim3(NQKV * CC / 2048), 256, 0, stream>>>(qkv_w, wqkvb, NQKV * CC);

  // 1) qkv = x @ qkv_w^T + b, fused RoPE + head-split (+0.125*log2e into Q)
  gemm_k<0><<<dim3(NQKV / 128, (BB * TT) / 128), 256, 0, stream>>>(
      xb, wqkvb, qkv_b, fcos, fsin, (void*)Qb, Kb, Vb);
  // 2) causal flash attention -> Ob (B*T, C) bf16 (overwrites xb)
  attn_k<<<dim3(BB * HH * 16), 256, 0, stream>>>(Qb, Kb, Vb, Ob);
  // 3) convert proj_w (Qb dead now), then out = Ob @ proj_w^T + proj_b (fp32)
  cvt_k<<<dim3(CC * CC / 2048), 256, 0, stream>>>(proj_w, wpb, CC * CC);
  gemm_k<1><<<dim3(CC / 128, (BB * TT) / 128), 256, 0, stream>>>(
      Ob, wpb, proj_b, nullptr, nullptr, d_out, nullptr, nullptr);
}

// Round 8
// 329.535 us; speedup vs baseline: 1.8317x; 1.0388x over previous
//
#include <hip/hip_runtime.h>
#include <stdint.h>

// Problem constants
#define BB 4
#define TT 2048
#define CC 1024
#define HH 16
#define DH 64
#define NQKV 3072

typedef __bf16 bf16_t;
typedef __attribute__((ext_vector_type(8))) __bf16 bf16x8;
typedef __attribute__((ext_vector_type(4))) float f32x4;

#define MFMA16(a, b, c) __builtin_amdgcn_mfma_f32_16x16x32_bf16((a), (b), (c), 0, 0, 0)

// async global->LDS, 16B per lane. LDS dest = wave-uniform base + lane*16.
__device__ __forceinline__ void gll16(const void* g, void* l) {
  typedef const __attribute__((address_space(1))) void* gp_t;
  typedef __attribute__((address_space(3))) void* lp_t;
  __builtin_amdgcn_global_load_lds((gp_t)(uintptr_t)g, (lp_t)(uintptr_t)l, 16, 0, 0);
}

// ---------------------------------------------------------------------------
// fp32 -> bf16 convert, 8 elems/thread (n multiple of 2048)
// ---------------------------------------------------------------------------
__global__ __launch_bounds__(256) void cvt_k(const float* __restrict__ src,
                                             bf16_t* __restrict__ dst, int n) {
  const int i8 = (blockIdx.x * 256 + threadIdx.x) * 8;
  if (i8 < n) {
    const f32x4 a = *(const f32x4*)(src + i8);
    const f32x4 b = *(const f32x4*)(src + i8 + 4);
    bf16x8 r;
    r[0] = (bf16_t)a[0]; r[1] = (bf16_t)a[1]; r[2] = (bf16_t)a[2]; r[3] = (bf16_t)a[3];
    r[4] = (bf16_t)b[0]; r[5] = (bf16_t)b[1]; r[6] = (bf16_t)b[2]; r[7] = (bf16_t)b[3];
    *(bf16x8*)(dst + i8) = r;
  }
}

// ---------------------------------------------------------------------------
// GEMM (bf16 A, bf16 W): C[m][n] = sum_k A[m][k]*W[n][k] (+bias[n]); K=1024.
// BK=64 staged as two BK=32 half-tiles (keeps 64B-row layout compatible with
// global_load_lds and 2-way-free bank access); 2 barriers per 64 k-steps.
// EPI==0: qkv epilogue (RoPE Q/K, 0.125*log2e folded into Q, scatter B,H,T,dh)
// EPI==1: bias epilogue into fp32 out0
// ---------------------------------------------------------------------------
template <int EPI>
__global__ __launch_bounds__(256) void gemm_k(
    const bf16_t* __restrict__ A, const bf16_t* __restrict__ W,
    const float* __restrict__ bias,
    const float* __restrict__ fcos, const float* __restrict__ fsin,
    void* __restrict__ out0v, bf16_t* __restrict__ out1,
    bf16_t* __restrict__ out2) {
  __shared__ bf16_t Alds[2][128 * 32];
  __shared__ bf16_t Blds[2][128 * 32];
  const int K = 1024;
  const int tid = threadIdx.x;
  const int lane = tid & 63, wave = tid >> 6;
  const int quad = lane >> 4, c = lane & 15;
  const int wm = wave >> 1, wn = wave & 1;
  const int mbase = blockIdx.y * 128, nbase = blockIdx.x * 128;

  f32x4 acc[4][4];
#pragma unroll
  for (int i = 0; i < 4; ++i)
#pragma unroll
    for (int j = 0; j < 4; ++j) acc[i][j] = (f32x4){0.f, 0.f, 0.f, 0.f};

  const int ch0 = tid, ch1 = tid + 256;  // 512 chunks of 16B per 128x32 half
  const bf16_t* ag0 = A + (mbase + (ch0 >> 2)) * K + (ch0 & 3) * 8;
  const bf16_t* ag1 = A + (mbase + (ch1 >> 2)) * K + (ch1 & 3) * 8;
  const bf16_t* bg0 = W + (nbase + (ch0 >> 2)) * K + (ch0 & 3) * 8;
  const bf16_t* bg1 = W + (nbase + (ch1 >> 2)) * K + (ch1 & 3) * 8;

  for (int k0 = 0; k0 < K; k0 += 64) {
    __syncthreads();  // previous tile's readers done
    gll16(ag0 + k0, &Alds[0][ch0 * 8]);
    gll16(ag1 + k0, &Alds[0][ch1 * 8]);
    gll16(bg0 + k0, &Blds[0][ch0 * 8]);
    gll16(bg1 + k0, &Blds[0][ch1 * 8]);
    gll16(ag0 + k0 + 32, &Alds[1][ch0 * 8]);
    gll16(ag1 + k0 + 32, &Alds[1][ch1 * 8]);
    gll16(bg0 + k0 + 32, &Blds[1][ch0 * 8]);
    gll16(bg1 + k0 + 32, &Blds[1][ch1 * 8]);
    __syncthreads();  // DMA drained
#pragma unroll
    for (int half = 0; half < 2; ++half) {
      bf16x8 af[4], bfr[4];
#pragma unroll
      for (int mi = 0; mi < 4; ++mi)
        af[mi] = *(const bf16x8*)&Alds[half][(wm * 64 + mi * 16 + c) * 32 + quad * 8];
#pragma unroll
      for (int ni = 0; ni < 4; ++ni)
        bfr[ni] = *(const bf16x8*)&Blds[half][(wn * 64 + ni * 16 + c) * 32 + quad * 8];
#pragma unroll
      for (int mi = 0; mi < 4; ++mi)
#pragma unroll
        for (int ni = 0; ni < 4; ++ni)
          acc[mi][ni] = MFMA16(af[mi], bfr[ni], acc[mi][ni]);
    }
  }

  // epilogue. C/D layout: col = lane&15 (+16*ni), row = quad*4 + r (+16*mi)
  const float qscale = 0.18033688011112042f;  // 0.125 * log2(e)
#pragma unroll
  for (int mi = 0; mi < 4; ++mi) {
#pragma unroll
    for (int ni = 0; ni < 4; ++ni) {
      const int n = nbase + wn * 64 + ni * 16 + c;
      const float bv = bias[n];
#pragma unroll
      for (int r = 0; r < 4; ++r) {
        const int m = mbase + wm * 64 + mi * 16 + quad * 4 + r;
        float v = acc[mi][ni][r] + bv;
        if (EPI == 0) {
          bf16_t* out0 = (bf16_t*)out0v;
          const int sel = n >> 10;  // 0=q 1=k 2=v
          const int nl = n & 1023;
          const int h = nl >> 6, d = nl & 63;
          const int b = m >> 11, t = m & 2047;
          const int dst = ((b * HH + h) * TT + t) * DH + d;
          if (sel < 2) {
            const float pv = __shfl_xor(v, 1, 64);  // RoPE partner (col n^1)
            const int d2 = d >> 1;
            const float cs = fcos[t * 32 + d2];
            const float sn = fsin[t * 32 + d2];
            float o = ((d & 1) == 0) ? (v * cs - pv * sn) : (pv * sn + v * cs);
            if (sel == 0) {
              o *= qscale;
              out0[dst] = (bf16_t)o;
            } else {
              out1[dst] = (bf16_t)o;
            }
          } else {
            out2[dst] = (bf16_t)v;
          }
        } else {
          float* outf = (float*)out0v;
          outf[m * CC + n] = v;
        }
      }
    }
  }
}

// ---------------------------------------------------------------------------
// Flash attention, causal. Q pre-scaled by 0.125*log2(e) (exp2 domain).
// Uniform-work causal pairing (R7): block handles q-tiles qtA=pair, qtB=31-pair
// sequentially -> exactly 33 kv-iterations per block. Grid 1024, 4 waves.
// R8: kv-loop unrolled x2 so the LDS buffer index is compile-time (address
// LICM); rowsum via 2 MFMAs against a ones-fragment; incremental global
// pointers. Swizzle formulas byte-identical to R5/R7 (0 bank conflicts).
// ---------------------------------------------------------------------------
__global__ __launch_bounds__(256, 4) void attn_k(const bf16_t* __restrict__ Q,
                                                 const bf16_t* __restrict__ Kv,
                                                 const bf16_t* __restrict__ V,
                                                 bf16_t* __restrict__ O) {
  __shared__ bf16_t KS[2][64 * 64];
  __shared__ bf16_t VtS[2][64 * 64];
  __shared__ bf16_t PS[4][16 * 64];

  const int tid = threadIdx.x;
  const int lane = tid & 63, wave = tid >> 6;
  const int quad = lane >> 4, c = lane & 15;
  const int bi = blockIdx.x;
  const int pair = bi & 15, h = (bi >> 4) & 15, b = bi >> 8;
  const int qtA = pair, qtB = 31 - pair;
  const int nA = qtA + 1;  // kv tiles in phase A

  const bf16_t* Qh = Q + ((b * HH + h) * TT) * DH;
  const bf16_t* Kh = Kv + ((b * HH + h) * TT) * DH;
  const bf16_t* Vh = V + ((b * HH + h) * TT) * DH;

  const f32x4 zero4 = {0.f, 0.f, 0.f, 0.f};
  bf16x8 ones8;
#pragma unroll
  for (int i = 0; i < 8; ++i) ones8[i] = (bf16_t)1.0f;

  // staging bases (per-thread, loop-invariant)
  const int krow0 = tid >> 3, kc8 = tid & 7, krow1 = krow0 + 32;
  const bf16_t* kbase0 = Kh + krow0 * DH + kc8 * 8;
  const bf16_t* kbase1 = Kh + krow1 * DH + kc8 * 8;
  const int vsb = tid >> 2, vjp = tid & 3;
  const int vrg = vsb & 7, vc8 = vsb >> 3;
  const int vd0 = vc8 * 8 + vjp * 2, vd1 = vd0 + 1;
  const bf16_t* vbase = Vh + vrg * 8 * DH + vd0;

  // invariant swizzled fragment offsets (elements): row c, chunk (quad|quad+4)
  const int sw = c & 7;
  const int e0 = c * 64 + (quad ^ sw) * 8;
  const int e1 = c * 64 + ((quad + 4) ^ sw) * 8;

  bf16x8 kr0, kr1;
  uint32_t vr[8];
  auto load_tile = [&](int eoff) {
    kr0 = *(const bf16x8*)(kbase0 + eoff);
    kr1 = *(const bf16x8*)(kbase1 + eoff);
    const bf16_t* vp = vbase + eoff;
#pragma unroll
    for (int i = 0; i < 8; ++i) vr[i] = *(const uint32_t*)(vp + i * DH);
  };
  auto store_tile = [&](int buf) {
    *(bf16x8*)&KS[buf][(krow0 * 8 + (kc8 ^ (krow0 & 7))) * 8] = kr0;
    *(bf16x8*)&KS[buf][(krow1 * 8 + (kc8 ^ (krow1 & 7))) * 8] = kr1;
    union { bf16x8 v; uint16_t u[8]; } colA, colB;
#pragma unroll
    for (int i = 0; i < 8; ++i) {
      colA.u[i] = (uint16_t)(vr[i] & 0xffffu);
      colB.u[i] = (uint16_t)(vr[i] >> 16);
    }
    *(bf16x8*)&VtS[buf][(vd0 * 8 + (vrg ^ (vd0 & 7))) * 8] = colA.v;
    *(bf16x8*)&VtS[buf][(vd1 * 8 + (vrg ^ (vd1 & 7))) * 8] = colB.v;
  };

  // phase state (A first)
  int qtbase = qtA * 64;
  bf16x8 qf0 = *(const bf16x8*)(Qh + (qtbase + wave * 16 + c) * DH + quad * 8);
  bf16x8 qf1 = *(const bf16x8*)(Qh + (qtbase + wave * 16 + c) * DH + 32 + quad * 8);

  f32x4 o_acc[4] = {zero4, zero4, zero4, zero4};
  float m_r[4] = {-1e30f, -1e30f, -1e30f, -1e30f};
  float l_r[4] = {0.f, 0.f, 0.f, 0.f};

  auto write_O = [&](int qtb) {
#pragma unroll
    for (int r = 0; r < 4; ++r) {
      const int qg = qtb + wave * 16 + quad * 4 + r;
      const float inv = 1.0f / l_r[r];
#pragma unroll
      for (int ni = 0; ni < 4; ++ni)
        O[(b * TT + qg) * CC + h * 64 + ni * 16 + c] =
            (bf16_t)(o_acc[ni][r] * inv);
    }
  };

  load_tile(0);
  store_tile(0);
  __syncthreads();
  int coff = 0;   // current tile element offset into K/V
  int kkey = 0;   // current tile key-index base

// one kv iteration; CUR is a literal 0/1 -> LDS addresses fold to constants
#define ATTN_ITER(FI, CUR)                                                     \
  {                                                                            \
    const int fi_ = (FI);                                                      \
    const bool pre_ = fi_ < 32;                                                \
    const int noff_ = (fi_ + 1 == nA) ? 0 : coff + 64 * DH;                    \
    if (pre_) load_tile(noff_);                                                \
    bf16x8 kf0[4], kf1[4];                                                     \
    _Pragma("unroll") for (int ni = 0; ni < 4; ++ni) {                         \
      kf0[ni] = *(const bf16x8*)&KS[CUR][ni * 1024 + e0];                      \
      kf1[ni] = *(const bf16x8*)&KS[CUR][ni * 1024 + e1];                      \
    }                                                                          \
    f32x4 s[4];                                                                \
    _Pragma("unroll") for (int ni = 0; ni < 4; ++ni) {                         \
      f32x4 t = MFMA16(qf0, kf0[ni], zero4);                                   \
      t = MFMA16(qf1, kf1[ni], t);                                             \
      s[ni] = t;                                                               \
    }                                                                          \
    const int minq_ = qtbase + wave * 16;                                      \
    if (kkey + 63 > minq_) {                                                   \
      _Pragma("unroll") for (int ni = 0; ni < 4; ++ni)                         \
          _Pragma("unroll") for (int r = 0; r < 4; ++r) {                      \
        const int key_ = kkey + ni * 16 + c;                                   \
        const int qg_ = minq_ + quad * 4 + r;                                  \
        if (key_ > qg_) s[ni][r] = -1e30f;                                     \
      }                                                                        \
    }                                                                          \
    float alpha[4];                                                            \
    _Pragma("unroll") for (int r = 0; r < 4; ++r) {                            \
      float mx = fmaxf(fmaxf(s[0][r], s[1][r]), fmaxf(s[2][r], s[3][r]));      \
      mx = fmaxf(mx, __shfl_xor(mx, 1, 64));                                   \
      mx = fmaxf(mx, __shfl_xor(mx, 2, 64));                                   \
      mx = fmaxf(mx, __shfl_xor(mx, 4, 64));                                   \
      mx = fmaxf(mx, __shfl_xor(mx, 8, 64));                                   \
      const float mnew = fmaxf(m_r[r], mx);                                    \
      alpha[r] = __builtin_amdgcn_exp2f(m_r[r] - mnew);                        \
      m_r[r] = mnew;                                                           \
    }                                                                          \
    _Pragma("unroll") for (int ni = 0; ni < 4; ++ni)                           \
        _Pragma("unroll") for (int r = 0; r < 4; ++r) {                        \
      const float p = __builtin_amdgcn_exp2f(s[ni][r] - m_r[r]);               \
      const int prow_ = quad * 4 + r, pcol_ = ni * 16 + c;                     \
      PS[wave][(prow_ * 8 + ((pcol_ >> 3) ^ (prow_ & 7))) * 8 + (pcol_ & 7)] = \
          (bf16_t)p;                                                           \
    }                                                                          \
    _Pragma("unroll") for (int r = 0; r < 4; ++r) {                            \
      _Pragma("unroll") for (int ni = 0; ni < 4; ++ni)                         \
          o_acc[ni][r] *= alpha[r];                                            \
    }                                                                          \
    asm volatile("s_waitcnt lgkmcnt(0)" ::: "memory");                         \
    const bf16x8 p0 = *(const bf16x8*)&PS[wave][e0];                           \
    const bf16x8 p1 = *(const bf16x8*)&PS[wave][e1];                           \
    f32x4 rs = MFMA16(p0, ones8, zero4);                                       \
    rs = MFMA16(p1, ones8, rs);                                                \
    _Pragma("unroll") for (int ni = 0; ni < 4; ++ni) {                         \
      const bf16x8 v0 = *(const bf16x8*)&VtS[CUR][ni * 1024 + e0];             \
      const bf16x8 v1 = *(const bf16x8*)&VtS[CUR][ni * 1024 + e1];             \
      o_acc[ni] = MFMA16(p0, v0, o_acc[ni]);                                   \
      o_acc[ni] = MFMA16(p1, v1, o_acc[ni]);                                   \
    }                                                                          \
    _Pragma("unroll") for (int r = 0; r < 4; ++r)                              \
        l_r[r] = l_r[r] * alpha[r] + rs[r];                                    \
    if (fi_ == nA - 1) {                                                       \
      write_O(qtbase);                                                         \
      qtbase = qtB * 64;                                                       \
      qf0 = *(const bf16x8*)(Qh + (qtbase + wave * 16 + c) * DH + quad * 8);   \
      qf1 = *(const bf16x8*)(Qh + (qtbase + wave * 16 + c) * DH + 32 +         \
                             quad * 8);                                        \
      _Pragma("unroll") for (int r = 0; r < 4; ++r) {                          \
        m_r[r] = -1e30f;                                                       \
        l_r[r] = 0.f;                                                          \
      }                                                                        \
      _Pragma("unroll") for (int ni = 0; ni < 4; ++ni) o_acc[ni] = zero4;      \
    }                                                                          \
    if (pre_) store_tile(1 - (CUR));                                           \
    __syncthreads();                                                           \
    coff = noff_;                                                              \
    kkey = (fi_ + 1 == nA) ? 0 : kkey + 64;                                    \
  }

  for (int fj = 0; fj < 16; ++fj) {
    ATTN_ITER(2 * fj, 0)
    ATTN_ITER(2 * fj + 1, 1)
  }
  ATTN_ITER(32, 0)
#undef ATTN_ITER

  write_O(qtbase);  // phase B epilogue
}

// ---------------------------------------------------------------------------
extern "C" void kernel_launch(void* const* d_in, const int* in_sizes, int n_in,
                              void* d_out, int out_size, void* d_ws,
                              size_t ws_size, hipStream_t stream) {
  // Resolve inputs by unique element-count signature.
  const float *x = nullptr, *fcos = nullptr, *fsin = nullptr;
  const float *qkv_w = nullptr, *qkv_b = nullptr, *proj_w = nullptr, *proj_b = nullptr;
  for (int i = 0; i < n_in; ++i) {
    const int s = in_sizes[i];
    const float* p = (const float*)d_in[i];
    if (s == BB * TT * CC) x = p;                        // 8388608
    else if (s == TT * (DH / 2)) { if (!fcos) fcos = p; else fsin = p; }
    else if (s == NQKV * CC) qkv_w = p;                  // 3145728
    else if (s == NQKV) qkv_b = p;                       // 3072
    else if (s == CC * CC) proj_w = p;                   // 1048576
    else if (s == CC) proj_b = p;                        // 1024
    // mask (TT*TT) unused; causality is structural
  }

  const size_t NE = (size_t)BB * TT * CC;  // 8388608
  bf16_t* Qb = (bf16_t*)d_ws;
  bf16_t* Kb = Qb + NE;
  bf16_t* Vb = Kb + NE;
  bf16_t* Ob = Vb + NE;
  // dead-region reuse (all hazard-free under stream ordering):
  bf16_t* xb = Ob;                 // x_bf16 lives in Ob region until attn
  bf16_t* wqkvb = (bf16_t*)d_out;  // qkv_w bf16 in d_out until gemm3 writes it
  bf16_t* wpb = Qb;                // proj_w bf16 in Qb region (dead after attn)

  // converts
  cvt_k<<<dim3((int)(NE / 2048)), 256, 0, stream>>>(x, xb, (int)NE);
  cvt_k<<<dim3(NQKV * CC / 2048), 256, 0, stream>>>(qkv_w, wqkvb, NQKV * CC);

  // 1) qkv = x @ qkv_w^T + b, fused RoPE + head-split (+0.125*log2e into Q)
  gemm_k<0><<<dim3(NQKV / 128, (BB * TT) / 128), 256, 0, stream>>>(
      xb, wqkvb, qkv_b, fcos, fsin, (void*)Qb, Kb, Vb);
  // 2) causal flash attention -> Ob (B*T, C) bf16 (overwrites xb)
  attn_k<<<dim3(BB * HH * 16), 256, 0, stream>>>(Qb, Kb, Vb, Ob);
  // 3) convert proj_w (Qb dead now), then out = Ob @ proj_w^T + proj_b (fp32)
  cvt_k<<<dim3(CC * CC / 2048), 256, 0, stream>>>(proj_w, wpb, CC * CC);
  gemm_k<1><<<dim3(CC / 128, (BB * TT) / 128), 256, 0, stream>>>(
      Ob, wpb, proj_b, nullptr, nullptr, d_out, nullptr, nullptr);
}